// Round 1
// baseline (55.334 us; speedup 1.0000x reference)
//
#include <hip/hip_runtime.h>
#include <hip/hip_bf16.h>

#define T 32
#define WAYS 64
#define SHOTS 8
#define CDIM 1024
#define WQ 1024
#define BM 64
#define BK 64

typedef float f32x4 __attribute__((ext_vector_type(4)));
typedef __bf16 bf16x8 __attribute__((ext_vector_type(8)));

// Kernel 1: proto = mean over shots (stored bf16), p_sq = ||proto||^2 (fp32)
__global__ __launch_bounds__(256) void proto_kernel(const float* __restrict__ support,
                                                    __bf16* __restrict__ proto,
                                                    float* __restrict__ p_sq) {
    const int bid = blockIdx.x;          // t*64 + way
    const int tid = threadIdx.x;         // 256 threads, 1 float4 of c each
    const float* sp = support + (size_t)bid * (SHOTS * CDIM);
    float4 a = make_float4(0.f, 0.f, 0.f, 0.f);
#pragma unroll
    for (int s = 0; s < SHOTS; ++s) {
        const float4 v = *reinterpret_cast<const float4*>(sp + s * CDIM + tid * 4);
        a.x += v.x; a.y += v.y; a.z += v.z; a.w += v.w;
    }
    a.x *= 0.125f; a.y *= 0.125f; a.z *= 0.125f; a.w *= 0.125f;
    float ps = a.x * a.x + a.y * a.y + a.z * a.z + a.w * a.w;

    union { __bf16 h[4]; uint2 u; } pk;
    pk.h[0] = (__bf16)a.x; pk.h[1] = (__bf16)a.y; pk.h[2] = (__bf16)a.z; pk.h[3] = (__bf16)a.w;
    *reinterpret_cast<uint2*>(proto + (size_t)bid * CDIM + tid * 4) = pk.u;

    // block-reduce ps
#pragma unroll
    for (int m = 32; m >= 1; m >>= 1) ps += __shfl_down(ps, m, 64);
    __shared__ float red[4];
    const int wv = tid >> 6, ln = tid & 63;
    if (ln == 0) red[wv] = ps;
    __syncthreads();
    if (tid == 0) p_sq[bid] = red[0] + red[1] + red[2] + red[3];
}

// Kernel 2: per-t GEMM  qp = Q[1024x1024] * P^T[1024x64], epilogue 2qp - qsq - psq
__global__ __launch_bounds__(256) void dist_kernel(const float* __restrict__ query,
                                                   const __bf16* __restrict__ proto,
                                                   const float* __restrict__ p_sq,
                                                   float* __restrict__ out) {
    const int bx = blockIdx.x;
    const int t  = bx >> 4;              // 16 m-tiles of 64 rows per t
    const int mt = bx & 15;
    const int tid  = threadIdx.x;
    const int lane = tid & 63;
    const int wv   = tid >> 6;

    __shared__ __bf16 As[BM * BK];       // XOR-swizzled
    __shared__ __bf16 Bs[WAYS * BK];     // XOR-swizzled
    __shared__ float qsq_s[BM];

    const float*  qbase = query + ((size_t)t * WQ + mt * BM) * CDIM;
    const __bf16* pbase = proto + (size_t)t * WAYS * CDIM;

    const int arow  = tid >> 4;          // 0..15 (row group for A staging)
    const int acol4 = tid & 15;          // float4 index within BK
    const int bway  = tid >> 3;          // 0..31
    const int boff  = tid & 7;           // 16B index within BK row

    float4 aReg[4];
    uint4  bReg[2];

    auto loadTile = [&](int ks) {
#pragma unroll
        for (int p = 0; p < 4; ++p)
            aReg[p] = *reinterpret_cast<const float4*>(
                qbase + (size_t)(p * 16 + arow) * CDIM + ks * BK + acol4 * 4);
#pragma unroll
        for (int p = 0; p < 2; ++p)
            bReg[p] = *reinterpret_cast<const uint4*>(
                pbase + (size_t)(p * 32 + bway) * CDIM + ks * BK + boff * 8);
    };

    loadTile(0);

    f32x4 acc[4];
#pragma unroll
    for (int n = 0; n < 4; ++n) acc[n] = (f32x4){0.f, 0.f, 0.f, 0.f};
    float qsqp[4] = {0.f, 0.f, 0.f, 0.f};

    for (int ks = 0; ks < CDIM / BK; ++ks) {
        // ---- write staged regs to LDS (convert A to bf16, accumulate qsq) ----
#pragma unroll
        for (int p = 0; p < 4; ++p) {
            const int row = p * 16 + arow;
            qsqp[p] += aReg[p].x * aReg[p].x + aReg[p].y * aReg[p].y +
                       aReg[p].z * aReg[p].z + aReg[p].w * aReg[p].w;
            union { __bf16 h[4]; uint2 u; } pk;
            pk.h[0] = (__bf16)aReg[p].x; pk.h[1] = (__bf16)aReg[p].y;
            pk.h[2] = (__bf16)aReg[p].z; pk.h[3] = (__bf16)aReg[p].w;
            const int byte = (row * 128 + acol4 * 8) ^ ((row & 7) << 4);
            *reinterpret_cast<uint2*>(reinterpret_cast<char*>(As) + byte) = pk.u;
        }
#pragma unroll
        for (int p = 0; p < 2; ++p) {
            const int way = p * 32 + bway;
            const int byte = (way * 128 + boff * 16) ^ ((way & 7) << 4);
            *reinterpret_cast<uint4*>(reinterpret_cast<char*>(Bs) + byte) = bReg[p];
        }
        __syncthreads();
        if (ks < CDIM / BK - 1) loadTile(ks + 1);   // overlap next loads with MFMA

        // ---- compute ----
#pragma unroll
        for (int ksub = 0; ksub < 2; ++ksub) {
            const int fr   = lane & 15;     // row (A) / col (B)
            const int kgrp = lane >> 4;     // k-group of 8
            const int arw  = wv * 16 + fr;
            const int abyte = (arw * 128 + ksub * 64 + kgrp * 16) ^ ((arw & 7) << 4);
            const bf16x8 af = *reinterpret_cast<const bf16x8*>(
                reinterpret_cast<char*>(As) + abyte);
#pragma unroll
            for (int n = 0; n < 4; ++n) {
                const int way = n * 16 + fr;
                const int bbyte = (way * 128 + ksub * 64 + kgrp * 16) ^ ((way & 7) << 4);
                const bf16x8 bfv = *reinterpret_cast<const bf16x8*>(
                    reinterpret_cast<char*>(Bs) + bbyte);
                acc[n] = __builtin_amdgcn_mfma_f32_16x16x32_bf16(af, bfv, acc[n], 0, 0, 0);
            }
        }
        __syncthreads();
    }

    // ---- q_sq: reduce per-row partials over the 16-lane load group ----
#pragma unroll
    for (int p = 0; p < 4; ++p) {
        float v = qsqp[p];
        v += __shfl_xor(v, 1, 64);
        v += __shfl_xor(v, 2, 64);
        v += __shfl_xor(v, 4, 64);
        v += __shfl_xor(v, 8, 64);
        if ((lane & 15) == 0) qsq_s[p * 16 + arow] = v;
    }
    __syncthreads();

    float psq[4];
#pragma unroll
    for (int n = 0; n < 4; ++n) psq[n] = p_sq[t * WAYS + n * 16 + (lane & 15)];

    const int crow0 = wv * 16 + (lane >> 4) * 4;
    float* obase = out + ((size_t)t * WQ + mt * BM) * WAYS;
#pragma unroll
    for (int n = 0; n < 4; ++n) {
#pragma unroll
        for (int r = 0; r < 4; ++r) {
            const int row = crow0 + r;
            const float v = 2.f * acc[n][r] - qsq_s[row] - psq[n];
            obase[(size_t)row * WAYS + n * 16 + (lane & 15)] = v;
        }
    }
}

extern "C" void kernel_launch(void* const* d_in, const int* in_sizes, int n_in,
                              void* d_out, int out_size, void* d_ws, size_t ws_size,
                              hipStream_t stream) {
    const float* query   = (const float*)d_in[0];
    const float* support = (const float*)d_in[1];
    float* out = (float*)d_out;

    __bf16* proto = (__bf16*)d_ws;                                   // 4 MB
    float*  p_sq  = (float*)((char*)d_ws + (size_t)T * WAYS * CDIM * sizeof(__bf16));

    hipLaunchKernelGGL(proto_kernel, dim3(T * WAYS), dim3(256), 0, stream,
                       support, proto, p_sq);
    hipLaunchKernelGGL(dist_kernel, dim3(T * 16), dim3(256), 0, stream,
                       query, proto, p_sq, out);
}